// Round 1
// baseline (107.266 us; speedup 1.0000x reference)
//
#include <hip/hip_runtime.h>
#include <math.h>

#define N_NODES 100000
#define N_EDGES 1000000
#define NB 8
#define NBUCK 256              // row buckets (full CU coverage)
#define BROWS 392              // rows per bucket; 256*392 = 100352 >= N
#define CAP 6144               // per-bucket capacity (expected ~3906 +- 6sigma)
#define NCHUNK 256             // edge chunks
#define CHUNKC 3907            // ceil(N_EDGES / NCHUNK)
#define ITER 8                 // ceil(CHUNKC / 512)

// ws layout:
// cursors[256*16] int   (row-bucket cursors, 1 live int / 64B)
// cntG[8] float         (per-graph node counts, global atomics)
// partial[256*512] float
// Y[512] float
// deg[N] float          (atomic accumulation of edge weights per col)
// db[N] uint2           {dinv_bits, batch}
// rowBin[256*CAP] uint2 {(c<<9)|(r%392), ew_bits}

__global__ __launch_bounds__(512) void kInit(int* __restrict__ cursors,
        float* __restrict__ deg, float* __restrict__ cntG) {
    const int t = blockIdx.x * 512 + threadIdx.x;
    if (t < NBUCK) cursors[t * 16] = t * CAP;
    if (t < NB) cntG[t] = 0.f;
    for (int i = t; i < N_NODES; i += 256 * 512) deg[i] = 0.f;
}

// One pass over the edge list: LDS histogram by row bucket -> cursor
// reservation -> block-local counting sort in LDS -> coalesced run writes.
// deg[col] accumulated directly with global atomics (replaces colBin).
__global__ __launch_bounds__(512) void kC(const int* __restrict__ row,
        const int* __restrict__ col, const float* __restrict__ ew,
        int* __restrict__ cursors, uint2* __restrict__ rowBin,
        float* __restrict__ deg) {
    __shared__ uint2 sPay[CHUNKC];              // 31256 B
    __shared__ unsigned char sBkt[CHUNKC];      // 3907 B
    __shared__ int hist[NBUCK], scan[NBUCK], gbase[NBUCK], off[NBUCK];
    const int tid = threadIdx.x;
    const int beg = blockIdx.x * CHUNKC;
    const int end = min(N_EDGES, beg + CHUNKC);

    if (tid < NBUCK) hist[tid] = 0;
    __syncthreads();

    int rx[ITER], cx[ITER]; float wv[ITER];
    #pragma unroll
    for (int it = 0; it < ITER; ++it) {
        const int i = beg + it * 512 + tid;
        if (i < end) {
            rx[it] = row[i]; cx[it] = col[i]; wv[it] = ew[i];
            atomicAdd(&hist[rx[it] / BROWS], 1);
            atomicAdd(&deg[cx[it]], wv[it]);        // fire-and-forget global atomic
        } else rx[it] = -1;
    }
    __syncthreads();

    // inclusive Hillis-Steele scan of hist (256 entries, 8 steps)
    if (tid < NBUCK) scan[tid] = hist[tid];
    __syncthreads();
    for (int s = 1; s < NBUCK; s <<= 1) {
        int v = 0;
        if (tid < NBUCK && tid >= s) v = scan[tid - s];
        __syncthreads();
        if (tid < NBUCK) scan[tid] += v;
        __syncthreads();
    }

    if (tid < NBUCK) {
        const int lb = scan[tid] - hist[tid];   // exclusive base within chunk
        scan[tid] = lb;
        off[tid] = lb;
        gbase[tid] = atomicAdd(&cursors[tid * 16], hist[tid]);
    }
    __syncthreads();

    #pragma unroll
    for (int it = 0; it < ITER; ++it) {
        if (rx[it] >= 0) {
            const int kb = rx[it] / BROWS;
            const int xl = rx[it] - kb * BROWS;  // < 392, fits 9 bits
            const int p = atomicAdd(&off[kb], 1);
            sPay[p] = make_uint2((unsigned)((cx[it] << 9) | xl),
                                 __float_as_uint(wv[it]));
            sBkt[p] = (unsigned char)kb;
        }
    }
    __syncthreads();

    const int T = end - beg;
    for (int j = tid; j < T; j += 512) {
        const int b = sBkt[j];
        const int dst = gbase[b] + (j - scan[b]);
        if (dst < (b + 1) * CAP) rowBin[dst] = sPay[j];   // overflow clamp
    }
}

// N-streaming: deg -> {dinv, batch}; per-graph node counts via LDS + 8 atomics/block
__global__ __launch_bounds__(512) void kDb(const float* __restrict__ deg,
        const int* __restrict__ batch, uint2* __restrict__ db,
        float* __restrict__ cntG) {
    __shared__ float cb[NB];
    const int tid = threadIdx.x;
    if (tid < NB) cb[tid] = 0.f;
    __syncthreads();
    const int i = blockIdx.x * 512 + tid;
    if (i < N_NODES) {
        const float dv = rsqrtf(deg[i] + 1.0f);   // + self-loop weight
        const int g = batch[i];
        db[i] = make_uint2(__float_as_uint(dv), (unsigned)g);
        atomicAdd(&cb[g], 1.0f);
    }
    __syncthreads();
    if (tid < NB) atomicAdd(&cntG[tid], cb[tid]);
}

// per row-bucket: LDS S-subtile accumulation (dinv[r] deferred) + fused partial-Y GEMV
__global__ __launch_bounds__(512) void kD_bucket(const float* __restrict__ X,
        const uint2* __restrict__ rowBin, const int* __restrict__ cursors,
        const uint2* __restrict__ db, float* __restrict__ partial) {
    __shared__ float Ssub[BROWS * NB];   // 12.5 KB
    __shared__ float red[512];
    const int tid = threadIdx.x;
    const int kb  = blockIdx.x;
    const int r0  = kb * BROWS;

    for (int i = tid; i < BROWS * NB; i += 512) Ssub[i] = 0.f;
    __syncthreads();

    const int beg = kb * CAP;
    const int end = min(cursors[kb * 16], beg + CAP);
    for (int i = beg + tid; i < end; i += 512) {
        const uint2 v = rowBin[i];
        const uint2 d = db[v.x >> 9];                 // {dinv[c], batch[c]}
        atomicAdd(&Ssub[((v.x & 511) << 3) | d.y],
                  __uint_as_float(d.x) * __uint_as_float(v.y));
    }
    if (tid < BROWS) {   // self-loop (dinv[r] applied at GEMV; /cnt at tail)
        const int r = r0 + tid;
        if (r < N_NODES) {
            const uint2 d = db[r];
            atomicAdd(&Ssub[(tid << 3) | d.y], __uint_as_float(d.x));
        }
    }
    __syncthreads();

    const int k4  = tid & 15;
    const int rid = tid >> 4;          // 32 rows in flight
    float acc[8][4];
    #pragma unroll
    for (int g = 0; g < 8; ++g)
        #pragma unroll
        for (int c = 0; c < 4; ++c) acc[g][c] = 0.f;

    for (int it = 0; it < (BROWS + 31) / 32; ++it) {
        const int lr = it * 32 + rid;
        const int r  = r0 + lr;
        if (lr < BROWS && r < N_NODES) {
            const float dv = __uint_as_float(db[r].x);
            const float4 x  = *reinterpret_cast<const float4*>(X + (long)r * 64 + k4 * 4);
            float4 s0 = *reinterpret_cast<const float4*>(&Ssub[lr * 8]);
            float4 s1 = *reinterpret_cast<const float4*>(&Ssub[lr * 8 + 4]);
            const float sg[8] = {s0.x * dv, s0.y * dv, s0.z * dv, s0.w * dv,
                                 s1.x * dv, s1.y * dv, s1.z * dv, s1.w * dv};
            #pragma unroll
            for (int g = 0; g < 8; ++g) {
                acc[g][0] += sg[g] * x.x;
                acc[g][1] += sg[g] * x.y;
                acc[g][2] += sg[g] * x.z;
                acc[g][3] += sg[g] * x.w;
            }
        }
    }

    #pragma unroll
    for (int g = 0; g < 8; ++g)
        #pragma unroll
        for (int c = 0; c < 4; ++c) {
            float v = acc[g][c];
            v += __shfl_xor(v, 16);
            v += __shfl_xor(v, 32);
            acc[g][c] = v;
        }

    red[tid] = 0.f;
    __syncthreads();
    if ((tid & 48) == 0) {
        #pragma unroll
        for (int g = 0; g < 8; ++g)
            #pragma unroll
            for (int c = 0; c < 4; ++c)
                atomicAdd(&red[g * 64 + k4 * 4 + c], acc[g][c]);
    }
    __syncthreads();
    partial[(long)kb * 512 + tid] = red[tid];
}

// 512 one-wave blocks: reduce partial -> Y[t]
__global__ __launch_bounds__(64) void k45_reduce(const float* __restrict__ partial,
        float* __restrict__ Y) {
    const int bid = blockIdx.x;
    const int lane = threadIdx.x;
    float s = 0.f;
    for (int b = lane; b < NBUCK; b += 64)
        s += partial[(long)b * 512 + bid];
    #pragma unroll
    for (int m = 1; m <= 32; m <<= 1) s += __shfl_xor(s, m);
    if (lane == 0) Y[bid] = s;
}

// single block: /cnt + z-gate + h-gate (LDS reused) + combine
__global__ __launch_bounds__(512) void kTail(const float* __restrict__ Y,
        const float* __restrict__ cnt, const float* __restrict__ H,
        const float* __restrict__ Wz, const float* __restrict__ bz,
        const float* __restrict__ lzW, const float* __restrict__ lzb,
        const float* __restrict__ Wh, const float* __restrict__ bh,
        const float* __restrict__ lhW, const float* __restrict__ lhb,
        float* __restrict__ out) {
    __shared__ float Ws[64 * 64];
    __shared__ float lWs[128 * 64];
    __shared__ float Ys[512], Hs[512], P[512], Gz[512];
    __shared__ float cnt_s[NB];
    const int t = threadIdx.x;
    const int g = t >> 6, j = t & 63;

    const float yv = Y[t];
    if (t < NB) cnt_s[t] = fmaxf(cnt[t], 1.0f);
    Hs[t] = H[t];
    {
        const float4* W4  = reinterpret_cast<const float4*>(Wz);
        const float4* lW4 = reinterpret_cast<const float4*>(lzW);
        float4* Ws4  = reinterpret_cast<float4*>(Ws);
        float4* lWs4 = reinterpret_cast<float4*>(lWs);
        #pragma unroll
        for (int i = 0; i < 2; ++i) Ws4[t + 512 * i] = W4[t + 512 * i];
        #pragma unroll
        for (int i = 0; i < 4; ++i) lWs4[t + 512 * i] = lW4[t + 512 * i];
    }
    __syncthreads();
    Ys[t] = yv / cnt_s[g];
    __syncthreads();

    float p = bz[j];
    #pragma unroll 8
    for (int k = 0; k < 64; ++k) p += Ys[g * 64 + k] * Ws[k * 64 + j];
    P[t] = p;
    __syncthreads();
    float az = lzb[j];
    #pragma unroll 8
    for (int k = 0; k < 64; ++k)
        az += P[g * 64 + k] * lWs[k * 64 + j] + Hs[g * 64 + k] * lWs[(64 + k) * 64 + j];
    Gz[t] = 1.f / (1.f + expf(-az));
    __syncthreads();

    {
        const float4* W4  = reinterpret_cast<const float4*>(Wh);
        const float4* lW4 = reinterpret_cast<const float4*>(lhW);
        float4* Ws4  = reinterpret_cast<float4*>(Ws);
        float4* lWs4 = reinterpret_cast<float4*>(lWs);
        #pragma unroll
        for (int i = 0; i < 2; ++i) Ws4[t + 512 * i] = W4[t + 512 * i];
        #pragma unroll
        for (int i = 0; i < 4; ++i) lWs4[t + 512 * i] = lW4[t + 512 * i];
    }
    __syncthreads();

    p = bh[j];
    #pragma unroll 8
    for (int k = 0; k < 64; ++k) p += Ys[g * 64 + k] * Ws[k * 64 + j];
    P[t] = p;
    __syncthreads();
    float ah = lhb[j];
    #pragma unroll 8
    for (int k = 0; k < 64; ++k)
        ah += P[g * 64 + k] * lWs[k * 64 + j] + Hs[g * 64 + k] * lWs[(64 + k) * 64 + j];
    const float Ht = tanhf(ah);

    out[t] = Gz[t] * Hs[t] + (1.f - Gz[t]) * Ht;
}

extern "C" void kernel_launch(void* const* d_in, const int* in_sizes, int n_in,
                              void* d_out, int out_size, void* d_ws, size_t ws_size,
                              hipStream_t stream) {
    (void)in_sizes; (void)n_in; (void)out_size; (void)ws_size;

    const float* X     = (const float*)d_in[0];
    const int*   ei    = (const int*)d_in[1];
    const int*   rowp  = ei;
    const int*   colp  = ei + N_EDGES;
    const int*   batch = (const int*)d_in[2];
    const float* ew    = (const float*)d_in[3];
    const float* H     = (const float*)d_in[4];
    const float* Wz  = (const float*)d_in[5];
    const float* bz  = (const float*)d_in[6];
    const float* lzW = (const float*)d_in[7];
    const float* lzb = (const float*)d_in[8];
    // gate r (d_in[9..12]) computed-but-unused in the reference -> skipped
    const float* Wh  = (const float*)d_in[13];
    const float* bh  = (const float*)d_in[14];
    const float* lhW = (const float*)d_in[15];
    const float* lhb = (const float*)d_in[16];
    float* out = (float*)d_out;

    int*   cursors = (int*)d_ws;                           // 256*16 ints
    float* cntG    = (float*)(cursors + NBUCK * 16);       // 8
    float* partial = cntG + NB;                            // 256*512
    float* Yv      = partial + (long)NBUCK * 512;          // 512
    float* deg     = Yv + 512;                             // N
    uint2* db      = (uint2*)(deg + N_NODES);              // N * 8B
    uint2* rowBin  = db + N_NODES;                         // 256*CAP * 8B

    kInit<<<256, 512, 0, stream>>>(cursors, deg, cntG);
    kC<<<NCHUNK, 512, 0, stream>>>(rowp, colp, ew, cursors, rowBin, deg);
    kDb<<<(N_NODES + 511) / 512, 512, 0, stream>>>(deg, batch, db, cntG);
    kD_bucket<<<NBUCK, 512, 0, stream>>>(X, rowBin, cursors, db, partial);
    k45_reduce<<<512, 64, 0, stream>>>(partial, Yv);
    kTail<<<1, 512, 0, stream>>>(Yv, cntG, H, Wz, bz, lzW, lzb, Wh, bh, lhW, lhb, out);
}

// Round 2
// 69.242 us; speedup vs baseline: 1.5491x; 1.5491x over previous
//
#include <hip/hip_runtime.h>
#include <math.h>

#define N_NODES 100000
#define N_EDGES 1000000
#define NB 8
#define NBUCK 256              // buckets per role; 512 cursors total
#define BROWS 392              // rows per bucket; 256*392 = 100352 >= N
#define CAP 6144               // per-bucket capacity (expected ~3906 +- 6sigma)
#define NCHUNK 256             // edge chunks
#define CHUNKC 3907            // ceil(N_EDGES / NCHUNK)
#define ITER 8                 // ceil(CHUNKC / 512)

// ws layout:
// cursors[512*16] int   (row cursors [0..256), col cursors [256..512); 1 live int / 64B)
// cntG[8] float         (per-graph node counts)
// partial[256*512] float
// Y[512] float
// db[N] uint2           {dinv_bits, batch}
// rowBin[256*CAP] uint2 {(c<<9)|(r%392), ew_bits}
// colBin[256*CAP] uint2 {c%392, ew_bits}

__global__ __launch_bounds__(512) void kInit(int* __restrict__ cursors,
        float* __restrict__ cntG) {
    const int t = threadIdx.x;
    const int b = (t < NBUCK) ? t : t - NBUCK;
    cursors[t * 16] = b * CAP;
    if (t < NB) cntG[t] = 0.f;
}

// Single pass over the edge list. Per 3907-edge chunk: dual LDS histogram
// (row-bucket + col-bucket) -> dual scan -> exact cursor reservation ->
// two block-local counting sorts (sPay reused) -> coalesced run writes.
// No global atomics, no alignment pads.
__global__ __launch_bounds__(512) void kC(const int* __restrict__ row,
        const int* __restrict__ col, const float* __restrict__ ew,
        int* __restrict__ cursors, uint2* __restrict__ rowBin,
        uint2* __restrict__ colBin) {
    __shared__ uint2 sPay[CHUNKC];              // 31256 B (reused by both roles)
    __shared__ unsigned char sBkt[CHUNKC];      // 3907 B
    __shared__ int hist[2 * NBUCK], scan[2 * NBUCK], gbase[2 * NBUCK], off[2 * NBUCK];
    const int tid = threadIdx.x;
    const int beg = blockIdx.x * CHUNKC;
    const int end = min(N_EDGES, beg + CHUNKC);
    const int T   = end - beg;

    hist[tid] = 0;
    __syncthreads();

    int rx[ITER], cx[ITER]; float wv[ITER];
    #pragma unroll
    for (int it = 0; it < ITER; ++it) {
        const int i = beg + it * 512 + tid;
        if (i < end) {
            rx[it] = row[i]; cx[it] = col[i]; wv[it] = ew[i];
            atomicAdd(&hist[rx[it] / BROWS], 1);
            atomicAdd(&hist[NBUCK + cx[it] / BROWS], 1);
        } else rx[it] = -1;
    }
    __syncthreads();

    // two independent inclusive scans (row half / col half), 8 steps
    scan[tid] = hist[tid];
    __syncthreads();
    for (int s = 1; s < NBUCK; s <<= 1) {
        const int l = tid & (NBUCK - 1);
        int v = 0;
        if (l >= s) v = scan[tid - s];
        __syncthreads();
        if (l >= s) scan[tid] += v;
        __syncthreads();
    }

    {
        const int eb = scan[tid] - hist[tid];      // exclusive base within chunk
        gbase[tid] = atomicAdd(&cursors[tid * 16], hist[tid]);
        scan[tid] = eb;
        off[tid] = eb;
    }
    __syncthreads();

    // ---- phase 1: row-binned payloads {(c<<9)|rl, ew} ----
    #pragma unroll
    for (int it = 0; it < ITER; ++it) {
        if (rx[it] >= 0) {
            const int kb = rx[it] / BROWS;
            const int xl = rx[it] - kb * BROWS;    // < 392, fits 9 bits
            const int p = atomicAdd(&off[kb], 1);
            sPay[p] = make_uint2((unsigned)((cx[it] << 9) | xl),
                                 __float_as_uint(wv[it]));
            sBkt[p] = (unsigned char)kb;
        }
    }
    __syncthreads();
    for (int j = tid; j < T; j += 512) {
        const int b = sBkt[j];
        const int dst = gbase[b] + (j - scan[b]);
        if (dst < (b + 1) * CAP) rowBin[dst] = sPay[j];
    }
    __syncthreads();

    // ---- phase 2: col-binned payloads {cl, ew} (sPay reused) ----
    #pragma unroll
    for (int it = 0; it < ITER; ++it) {
        if (rx[it] >= 0) {
            const int kb = cx[it] / BROWS;
            const int xl = cx[it] - kb * BROWS;
            const int p = atomicAdd(&off[NBUCK + kb], 1);
            sPay[p] = make_uint2((unsigned)xl, __float_as_uint(wv[it]));
            sBkt[p] = (unsigned char)kb;
        }
    }
    __syncthreads();
    for (int j = tid; j < T; j += 512) {
        const int b = sBkt[j];
        const int dst = gbase[NBUCK + b] + (j - scan[NBUCK + b]);
        if (dst < (b + 1) * CAP) colBin[dst] = sPay[j];
    }
}

// per col-bucket: LDS deg accumulation -> packed {dinv, batch}; per-graph counts
__global__ __launch_bounds__(512) void kD_degacc(const uint2* __restrict__ colBin,
        const int* __restrict__ cursors, const int* __restrict__ batch,
        uint2* __restrict__ db, float* __restrict__ cntG) {
    __shared__ float degsub[BROWS];
    __shared__ float cb[NB];
    const int tid = threadIdx.x;
    const int kb  = blockIdx.x;
    if (tid < BROWS) degsub[tid] = 0.f;
    if (tid < NB) cb[tid] = 0.f;
    __syncthreads();
    const int beg = kb * CAP;
    const int end = min(cursors[(NBUCK + kb) * 16], beg + CAP);
    for (int i = beg + tid; i < end; i += 512) {
        const uint2 v = colBin[i];
        atomicAdd(&degsub[v.x], __uint_as_float(v.y));
    }
    __syncthreads();
    if (tid < BROWS) {
        const int r = kb * BROWS + tid;
        if (r < N_NODES) {
            const float dv = rsqrtf(degsub[tid] + 1.0f);   // + self-loop weight
            const int g = batch[r];
            db[r] = make_uint2(__float_as_uint(dv), (unsigned)g);
            atomicAdd(&cb[g], 1.0f);
        }
    }
    __syncthreads();
    if (tid < NB) atomicAdd(&cntG[tid], cb[tid]);
}

// per row-bucket: LDS S-subtile accumulation (dinv[r] deferred) + fused partial-Y GEMV
__global__ __launch_bounds__(512) void kD_bucket(const float* __restrict__ X,
        const uint2* __restrict__ rowBin, const int* __restrict__ cursors,
        const uint2* __restrict__ db, float* __restrict__ partial) {
    __shared__ float Ssub[BROWS * NB];   // 12.5 KB
    __shared__ float red[512];
    const int tid = threadIdx.x;
    const int kb  = blockIdx.x;
    const int r0  = kb * BROWS;

    for (int i = tid; i < BROWS * NB; i += 512) Ssub[i] = 0.f;
    __syncthreads();

    const int beg = kb * CAP;
    const int end = min(cursors[kb * 16], beg + CAP);
    for (int i = beg + tid; i < end; i += 512) {
        const uint2 v = rowBin[i];
        const uint2 d = db[v.x >> 9];                 // {dinv[c], batch[c]}
        atomicAdd(&Ssub[((v.x & 511) << 3) | d.y],
                  __uint_as_float(d.x) * __uint_as_float(v.y));
    }
    if (tid < BROWS) {   // self-loop (dinv[r] applied at GEMV; /cnt at tail)
        const int r = r0 + tid;
        if (r < N_NODES) {
            const uint2 d = db[r];
            atomicAdd(&Ssub[(tid << 3) | d.y], __uint_as_float(d.x));
        }
    }
    __syncthreads();

    const int k4  = tid & 15;
    const int rid = tid >> 4;          // 32 rows in flight
    float acc[8][4];
    #pragma unroll
    for (int g = 0; g < 8; ++g)
        #pragma unroll
        for (int c = 0; c < 4; ++c) acc[g][c] = 0.f;

    for (int it = 0; it < (BROWS + 31) / 32; ++it) {
        const int lr = it * 32 + rid;
        const int r  = r0 + lr;
        if (lr < BROWS && r < N_NODES) {
            const float dv = __uint_as_float(db[r].x);
            const float4 x  = *reinterpret_cast<const float4*>(X + (long)r * 64 + k4 * 4);
            float4 s0 = *reinterpret_cast<const float4*>(&Ssub[lr * 8]);
            float4 s1 = *reinterpret_cast<const float4*>(&Ssub[lr * 8 + 4]);
            const float sg[8] = {s0.x * dv, s0.y * dv, s0.z * dv, s0.w * dv,
                                 s1.x * dv, s1.y * dv, s1.z * dv, s1.w * dv};
            #pragma unroll
            for (int g = 0; g < 8; ++g) {
                acc[g][0] += sg[g] * x.x;
                acc[g][1] += sg[g] * x.y;
                acc[g][2] += sg[g] * x.z;
                acc[g][3] += sg[g] * x.w;
            }
        }
    }

    #pragma unroll
    for (int g = 0; g < 8; ++g)
        #pragma unroll
        for (int c = 0; c < 4; ++c) {
            float v = acc[g][c];
            v += __shfl_xor(v, 16);
            v += __shfl_xor(v, 32);
            acc[g][c] = v;
        }

    red[tid] = 0.f;
    __syncthreads();
    if ((tid & 48) == 0) {
        #pragma unroll
        for (int g = 0; g < 8; ++g)
            #pragma unroll
            for (int c = 0; c < 4; ++c)
                atomicAdd(&red[g * 64 + k4 * 4 + c], acc[g][c]);
    }
    __syncthreads();
    partial[(long)kb * 512 + tid] = red[tid];
}

// 512 one-wave blocks: reduce partial -> Y[t]
__global__ __launch_bounds__(64) void k45_reduce(const float* __restrict__ partial,
        float* __restrict__ Y) {
    const int bid = blockIdx.x;
    const int lane = threadIdx.x;
    float s = 0.f;
    for (int b = lane; b < NBUCK; b += 64)
        s += partial[(long)b * 512 + bid];
    #pragma unroll
    for (int m = 1; m <= 32; m <<= 1) s += __shfl_xor(s, m);
    if (lane == 0) Y[bid] = s;
}

// single block: /cnt + z-gate + h-gate (LDS reused) + combine
__global__ __launch_bounds__(512) void kTail(const float* __restrict__ Y,
        const float* __restrict__ cnt, const float* __restrict__ H,
        const float* __restrict__ Wz, const float* __restrict__ bz,
        const float* __restrict__ lzW, const float* __restrict__ lzb,
        const float* __restrict__ Wh, const float* __restrict__ bh,
        const float* __restrict__ lhW, const float* __restrict__ lhb,
        float* __restrict__ out) {
    __shared__ float Ws[64 * 64];
    __shared__ float lWs[128 * 64];
    __shared__ float Ys[512], Hs[512], P[512], Gz[512];
    __shared__ float cnt_s[NB];
    const int t = threadIdx.x;
    const int g = t >> 6, j = t & 63;

    const float yv = Y[t];
    if (t < NB) cnt_s[t] = fmaxf(cnt[t], 1.0f);
    Hs[t] = H[t];
    {
        const float4* W4  = reinterpret_cast<const float4*>(Wz);
        const float4* lW4 = reinterpret_cast<const float4*>(lzW);
        float4* Ws4  = reinterpret_cast<float4*>(Ws);
        float4* lWs4 = reinterpret_cast<float4*>(lWs);
        #pragma unroll
        for (int i = 0; i < 2; ++i) Ws4[t + 512 * i] = W4[t + 512 * i];
        #pragma unroll
        for (int i = 0; i < 4; ++i) lWs4[t + 512 * i] = lW4[t + 512 * i];
    }
    __syncthreads();
    Ys[t] = yv / cnt_s[g];
    __syncthreads();

    float p = bz[j];
    #pragma unroll 8
    for (int k = 0; k < 64; ++k) p += Ys[g * 64 + k] * Ws[k * 64 + j];
    P[t] = p;
    __syncthreads();
    float az = lzb[j];
    #pragma unroll 8
    for (int k = 0; k < 64; ++k)
        az += P[g * 64 + k] * lWs[k * 64 + j] + Hs[g * 64 + k] * lWs[(64 + k) * 64 + j];
    Gz[t] = 1.f / (1.f + expf(-az));
    __syncthreads();

    {
        const float4* W4  = reinterpret_cast<const float4*>(Wh);
        const float4* lW4 = reinterpret_cast<const float4*>(lhW);
        float4* Ws4  = reinterpret_cast<float4*>(Ws);
        float4* lWs4 = reinterpret_cast<float4*>(lWs);
        #pragma unroll
        for (int i = 0; i < 2; ++i) Ws4[t + 512 * i] = W4[t + 512 * i];
        #pragma unroll
        for (int i = 0; i < 4; ++i) lWs4[t + 512 * i] = lW4[t + 512 * i];
    }
    __syncthreads();

    p = bh[j];
    #pragma unroll 8
    for (int k = 0; k < 64; ++k) p += Ys[g * 64 + k] * Ws[k * 64 + j];
    P[t] = p;
    __syncthreads();
    float ah = lhb[j];
    #pragma unroll 8
    for (int k = 0; k < 64; ++k)
        ah += P[g * 64 + k] * lWs[k * 64 + j] + Hs[g * 64 + k] * lWs[(64 + k) * 64 + j];
    const float Ht = tanhf(ah);

    out[t] = Gz[t] * Hs[t] + (1.f - Gz[t]) * Ht;
}

extern "C" void kernel_launch(void* const* d_in, const int* in_sizes, int n_in,
                              void* d_out, int out_size, void* d_ws, size_t ws_size,
                              hipStream_t stream) {
    (void)in_sizes; (void)n_in; (void)out_size; (void)ws_size;

    const float* X     = (const float*)d_in[0];
    const int*   ei    = (const int*)d_in[1];
    const int*   rowp  = ei;
    const int*   colp  = ei + N_EDGES;
    const int*   batch = (const int*)d_in[2];
    const float* ew    = (const float*)d_in[3];
    const float* H     = (const float*)d_in[4];
    const float* Wz  = (const float*)d_in[5];
    const float* bz  = (const float*)d_in[6];
    const float* lzW = (const float*)d_in[7];
    const float* lzb = (const float*)d_in[8];
    // gate r (d_in[9..12]) computed-but-unused in the reference -> skipped
    const float* Wh  = (const float*)d_in[13];
    const float* bh  = (const float*)d_in[14];
    const float* lhW = (const float*)d_in[15];
    const float* lhb = (const float*)d_in[16];
    float* out = (float*)d_out;

    const long NCAP = (long)NBUCK * CAP;
    int*   cursors = (int*)d_ws;                           // 512*16 ints
    float* cntG    = (float*)(cursors + 2 * NBUCK * 16);   // 8
    float* partial = cntG + NB;                            // 256*512
    float* Yv      = partial + (long)NBUCK * 512;          // 512
    uint2* db      = (uint2*)(Yv + 512);                   // N * 8B
    uint2* rowBin  = db + N_NODES;                         // NCAP * 8B
    uint2* colBin  = rowBin + NCAP;                        // NCAP * 8B

    kInit<<<1, 512, 0, stream>>>(cursors, cntG);
    kC<<<NCHUNK, 512, 0, stream>>>(rowp, colp, ew, cursors, rowBin, colBin);
    kD_degacc<<<NBUCK, 512, 0, stream>>>(colBin, cursors, batch, db, cntG);
    kD_bucket<<<NBUCK, 512, 0, stream>>>(X, rowBin, cursors, db, partial);
    k45_reduce<<<512, 64, 0, stream>>>(partial, Yv);
    kTail<<<1, 512, 0, stream>>>(Yv, cntG, H, Wz, bz, lzW, lzb, Wh, bh, lhW, lhb, out);
}